// Round 4
// baseline (261.386 us; speedup 1.0000x reference)
//
#include <hip/hip_runtime.h>

// ---------------- problem constants ----------------
#define NB        8
#define NPB       120000
#define NPTS      (NB * NPB)       // 960000
#define MAX_PTS   10
#define MAX_VOX   40000
#define GX        704
#define GY        800
#define GZ        20

// Unified hash, robin-hood atomicMin insert. key = (lid<<32)|idx, EMPTY=max.
// Leadership decided inline: flag pre-init 1; every same-cell fold defeats
// exactly one idx (the max) -> flag[loser]=0 (~480/batch scattered u8 stores).
// R4: 4 points/thread -> 4 independent atomicMins in flight per lane.
// Grid 944 blocks = 3776 waves, all resident -> ~2x peak outstanding atomics
// vs R3 (which was 58% occupancy, 1 atomic/lane). Discriminates latency-bound
// (expect ~35 us) from coherence-point-throughput-bound (expect ~50 us).
#define HC2       (1 << 18)
#define HMASK2    (HC2 - 1)
#define NSLOT2    (NB * HC2)       // 2,097,152 slots, 16 MB

#define IPT       4                 // points per thread in k_insert
#define ITILE     (256 * IPT)       // 1024 points per block
#define ITILES    ((NPB + ITILE - 1) / ITILE)   // 118

#define TILES     469              // ceil(120000 / 256)
#define TILES_PAD 512
#define MBCAP     8192             // per-batch multi list capacity (~500 expected)
#define MTILE     2048

#define EMPTY64   0xFFFFFFFFFFFFFFFFull

// output layout (flat float32)
#define OUT_VOX   0LL
#define OUT_NUM   12800000LL
#define OUT_COOR  13120000LL
#define OUT_GRID  14400000LL

typedef float f4v __attribute__((ext_vector_type(4)));

__device__ __forceinline__ void nt_store4(float* p, float a, float b, float c, float d) {
    f4v v = {a, b, c, d};
    __builtin_nontemporal_store(v, (f4v*)p);
}

__device__ __forceinline__ bool point_cell(const float* __restrict__ p,
                                           int& cx, int& cy, int& cz) {
    // must match numpy f32: floor((xyz - PC_MIN) / VSIZE)
    cx = (int)floorf((p[1] - 0.0f)   / 0.1f);
    cy = (int)floorf((p[2] - (-40.0f)) / 0.1f);
    cz = (int)floorf((p[3] - (-3.0f))  / 0.2f);
    return (cx >= 0) & (cx < GX) & (cy >= 0) & (cy < GY) & (cz >= 0) & (cz < GZ);
}

__device__ __forceinline__ unsigned cell_hash(int lid) {
    return (((unsigned)lid * 2654435761u) >> 14) & HMASK2;
}

// ---------------- K0: init hash (EMPTY) + flag (=1) + mcount + grid_size ----------------
__global__ void k_init(float* __restrict__ out, ulonglong2* __restrict__ slab2,
                       uint4* __restrict__ flag4, unsigned* __restrict__ mcount) {
    int b = blockIdx.x & 7;
    int i = (blockIdx.x >> 3) * 256 + threadIdx.x;     // 0..131071 per batch
    ulonglong2 e2; e2.x = EMPTY64; e2.y = EMPTY64;
    slab2[(size_t)b * (HC2 / 2) + i] = e2;             // 16 MB total
    if (i < NPB / 16) {                                // 7500 uint4 per batch
        uint4 o1; o1.x = o1.y = o1.z = o1.w = 0x01010101u;
        flag4[b * (NPB / 16) + i] = o1;                // flag = 1 (assume leader)
    }
    if (blockIdx.x == 0 && threadIdx.x < NB) mcount[threadIdx.x * 16] = 0u;
    if (blockIdx.x == 0 && threadIdx.x == 0) {
        out[OUT_GRID + 0] = 704.f;
        out[OUT_GRID + 1] = 800.f;
        out[OUT_GRID + 2] = 20.f;
    }
}

// ---------------- K1: 4-way ILP robin-hood atomicMin insert + inline defeat-marking ----------------
// All loops #pragma unroll so key/h/old/act arrays are statically-indexed
// registers (rule #20: runtime-indexed arrays spill to scratch).
__global__ void k_insert(const float* __restrict__ pts,
                         unsigned long long* __restrict__ slabB,
                         int* __restrict__ lid32, unsigned char* __restrict__ flag) {
    int b = blockIdx.x & 7;
    int base = (blockIdx.x >> 3) * ITILE + threadIdx.x;
    unsigned long long* tb = slabB + (size_t)b * HC2;

    unsigned long long key[IPT];
    unsigned h[IPT];
    bool act[IPT];
    #pragma unroll
    for (int k = 0; k < IPT; k++) {
        int idx = base + k * 256;
        act[k] = (idx < NPB);
        if (act[k]) {
            int g = b * NPB + idx;
            const float* p = pts + (long long)g * 5;
            int cx, cy, cz;
            bool v = point_cell(p, cx, cy, cz);
            if (v) {
                int lid = (cz * GY + cy) * GX + cx;
                lid32[g] = lid;
                h[k] = cell_hash(lid);
                key[k] = ((unsigned long long)(unsigned)lid << 32)
                       | (unsigned long long)(unsigned)idx;
            } else {
                lid32[g] = -1;
                flag[g] = 0;
                act[k] = false;
            }
        }
    }

    // issue all atomics back-to-back (independent; resolved below)
    unsigned long long old[IPT];
    #pragma unroll
    for (int k = 0; k < IPT; k++)
        if (act[k]) old[k] = atomicMin(&tb[h[k]], key[k]);

    #pragma unroll
    for (int k = 0; k < IPT; k++) {
        if (!act[k]) continue;
        unsigned long long kk = key[k];
        unsigned long long oo = old[k];
        unsigned hh = h[k];
        while (true) {
            if (oo == EMPTY64) break;                  // filled an empty slot
            if ((oo >> 32) == (kk >> 32)) {            // same cell: one idx defeated
                unsigned loser = (oo > kk) ? (unsigned)oo : (unsigned)kk;
                flag[b * NPB + (int)loser] = 0;        // rare (~480/batch)
                break;
            }
            if (oo > kk) kk = oo;                      // displaced foreign entry: carry it
            hh = (hh + 1) & HMASK2;
            oo = atomicMin(&tb[hh], kk);
        }
    }
}

// ---------------- K2: per-tile leader counts (1 wave per 256-point tile) ----------------
__global__ void k_count(const unsigned* __restrict__ flag32, int* __restrict__ tileSum) {
    int w = blockIdx.x * 4 + ((int)threadIdx.x >> 6);  // 0..3751
    int lane = threadIdx.x & 63;
    int b = w & 7;
    int tile = w >> 3;
    int i = tile * 64 + lane;                          // uint index within batch
    unsigned x = (i < NPB / 4) ? flag32[b * (NPB / 4) + i] : 0u;
    int s = (int)((x * 0x01010101u) >> 24);            // byte-sum (each byte 0/1)
    #pragma unroll
    for (int off = 32; off; off >>= 1) s += __shfl_down(s, off);
    if (lane == 0) tileSum[b * TILES_PAD + tile] = s;
}

// ---------------- K3: fused scans + leader writes; non-leaders -> mlist ----------------
// Output rows/coors/num written non-temporally (write-once, never re-read by
// this kernel) to keep flag/lid32/tileSum resident in L2.
__global__ void k_finish(const float* __restrict__ pts, const int* __restrict__ lid32,
                         const unsigned char* __restrict__ flag,
                         const int* __restrict__ tileSum,
                         const unsigned long long* __restrict__ slabB,
                         float* __restrict__ out, unsigned short* __restrict__ slotOf,
                         int2* __restrict__ mlist, unsigned* __restrict__ mcount) {
    int b = blockIdx.x & 7;
    int tile = blockIdx.x >> 3;
    int t = threadIdx.x;

    __shared__ int sc[256];
    __shared__ int soff[TILES_PAD];
    // --- scan A: exclusive scan over tile sums (pairs) ---
    int v0 = (2 * t     < TILES) ? tileSum[b * TILES_PAD + 2 * t]     : 0;
    int v1 = (2 * t + 1 < TILES) ? tileSum[b * TILES_PAD + 2 * t + 1] : 0;
    int w = v0 + v1;
    sc[t] = w;
    __syncthreads();
    for (int off = 1; off < 256; off <<= 1) {
        int x = sc[t];
        if (t >= off) x += sc[t - off];
        __syncthreads();
        sc[t] = x;
        __syncthreads();
    }
    int e = sc[t] - w;
    soff[2 * t] = e;
    soff[2 * t + 1] = e + v0;
    __syncthreads();

    // --- scan B: in-tile leader rank from flag ---
    int idx = tile * 256 + t;
    int g = b * NPB + idx;
    int f = (idx < NPB) ? (int)flag[g] : 0;
    sc[t] = f;
    __syncthreads();
    for (int off = 1; off < 256; off <<= 1) {
        int x = sc[t];
        if (t >= off) x += sc[t - off];
        __syncthreads();
        sc[t] = x;
        __syncthreads();
    }
    int rank = sc[t] - f;                      // exclusive in-tile rank
    // no __syncthreads below this point

    if (idx >= NPB) return;
    int lid = lid32[g];
    if (lid < 0) return;                       // invalid point

    if (f) {                                   // leader (== cell's min idx == pos 0)
        int slot = soff[tile] + rank;
        slotOf[g] = (unsigned short)(slot < 65535 ? slot : 65535);  // before clip!
        if (slot >= MAX_VOX) return;
        unsigned ul = (unsigned)lid;
        unsigned cx = ul % (unsigned)GX;
        unsigned tt = ul / (unsigned)GX;
        unsigned cy = tt % (unsigned)GY;
        unsigned cz = tt / (unsigned)GY;
        long long r = (long long)b * MAX_VOX + slot;
        nt_store4(out + OUT_COOR + r * 4, (float)b, (float)cz, (float)cy, (float)cx);
        __builtin_nontemporal_store(1.f, out + OUT_NUM + r);  // multi fixed by k_multi
        const float* p = pts + (long long)g * 5;
        float* row = out + OUT_VOX + r * (MAX_PTS * 4);
        nt_store4(row, p[1], p[2], p[3], p[4]);
        #pragma unroll
        for (int i = 1; i < MAX_PTS; i++)
            nt_store4(row + i * 4, 0.f, 0.f, 0.f, 0.f);
    } else {
        // valid non-leader => multi cell (rare, ~480/batch): probe for leader idx.
        const unsigned long long* base = slabB + (size_t)b * HC2;
        unsigned h = cell_hash(lid);
        unsigned long long cur;
        while (true) {
            cur = base[h];
            if ((unsigned)(cur >> 32) == (unsigned)lid) break;
            h = (h + 1) & HMASK2;
        }
        unsigned minidx = (unsigned)cur;
        unsigned m = atomicAdd(&mcount[b * 16], 1u);
        if (m < MBCAP) mlist[(size_t)b * MBCAP + m] = make_int2((int)minidx, idx);
    }
}

// ---------------- K4: rank + scatter multi-cell non-leaders; fix num ----------------
__global__ void k_multi(const float* __restrict__ pts,
                        const int2* __restrict__ mlist, const unsigned* __restrict__ mcount,
                        const unsigned short* __restrict__ slotOf,
                        float* __restrict__ out) {
    int b = blockIdx.y;
    unsigned n = mcount[b * 16];
    if (n > MBCAP) n = MBCAP;
    unsigned t = blockIdx.x * blockDim.x + threadIdx.x;
    const int2* lst = mlist + (size_t)b * MBCAP;
    bool active = (t < n);
    int2 e = active ? lst[t] : make_int2(-1, -1);   // (leaderIdx, idx)
    int pos = 1;                                    // leader (not in list) is pos 0
    int same = 0;                                   // same-cell entries incl. self
    __shared__ int2 sm[MTILE];
    for (unsigned chunk = 0; chunk < n; chunk += MTILE) {
        unsigned m = n - chunk;
        if (m > MTILE) m = MTILE;
        for (unsigned i = threadIdx.x; i < m; i += 256)
            sm[i] = lst[chunk + i];
        __syncthreads();
        if (active) {
            #pragma unroll 4
            for (unsigned j = 0; j < m; j++) {
                int2 o = sm[j];
                if (o.x == e.x) { same++; if (o.y < e.y) pos++; }
            }
        }
        __syncthreads();
    }
    if (!active) return;
    int slot = (int)slotOf[(size_t)b * NPB + e.x];
    if (slot >= MAX_VOX) return;
    if (pos == 1) {                                 // smallest non-leader writes true count
        int cnt = same + 1;                         // + leader
        out[OUT_NUM + (long long)b * MAX_VOX + slot] =
            (float)(cnt < MAX_PTS ? cnt : MAX_PTS);
    }
    if (pos >= MAX_PTS) return;
    const float* p = pts + ((long long)b * NPB + e.y) * 5;
    ((float4*)(out + OUT_VOX))[(long long)(b * MAX_VOX + slot) * MAX_PTS + pos] =
        make_float4(p[1], p[2], p[3], p[4]);
}

extern "C" void kernel_launch(void* const* d_in, const int* in_sizes, int n_in,
                              void* d_out, int out_size, void* d_ws, size_t ws_size,
                              hipStream_t stream) {
    const float* pts = (const float*)d_in[0];
    float* out = (float*)d_out;

    char* w = (char*)d_ws;
    unsigned long long* slabB = (unsigned long long*)w;
    w += (size_t)NSLOT2 * 8;                                               // 16 MB
    int2* mlist = (int2*)w;  w += (size_t)NB * MBCAP * 8;                  // 0.5 MB
    int* lid32 = (int*)w;    w += (size_t)NPTS * 4;                        // 3.84 MB
    int* tileSum = (int*)w;  w += (size_t)NB * TILES_PAD * 4;              // 16 KB
    unsigned* mcount = (unsigned*)w; w += (size_t)NB * 16 * 4;             // 512 B
    unsigned short* slotOf = (unsigned short*)w; w += (size_t)NPTS * 2;    // 1.92 MB
    unsigned char* flag = (unsigned char*)w;  w += (size_t)NPTS;           // 0.96 MB (16B-aligned)

    const int PB = TILES * NB;      // 3752 blocks for per-point kernels
    k_init<<<dim3(NB * (HC2 / 2 / 256)), dim3(256), 0, stream>>>(out, (ulonglong2*)slabB,
                                                                 (uint4*)flag, mcount);
    k_insert<<<dim3(ITILES * NB), dim3(256), 0, stream>>>(pts, slabB, lid32, flag);
    k_count<<<dim3((TILES * NB + 3) / 4), dim3(256), 0, stream>>>((const unsigned*)flag, tileSum);
    k_finish<<<dim3(PB), dim3(256), 0, stream>>>(pts, lid32, flag, tileSum, slabB,
                                                 out, slotOf, mlist, mcount);
    k_multi<<<dim3(MBCAP / 256, NB), dim3(256), 0, stream>>>(pts, mlist, mcount, slotOf, out);
}

// Round 5
// 176.791 us; speedup vs baseline: 1.4785x; 1.4785x over previous
//
#include <hip/hip_runtime.h>

// ---------------- problem constants ----------------
#define NB        8
#define NPB       120000
#define NPTS      (NB * NPB)       // 960000
#define MAX_PTS   10
#define MAX_VOX   40000
#define GX        704
#define GY        800
#define GZ        20

// Unified hash, robin-hood atomicMin insert. key = (lid<<32)|idx, EMPTY=max.
// Leadership decided inline: flag pre-init 1; every same-cell fold defeats
// exactly one idx (the max) -> flag[loser]=0 (~480/batch scattered u8 stores).
// R5: voxel zero-fill moved to k_init as a CONTIGUOUS NT stream (R4 lesson:
// NT on scattered 160B islands = 3.5x write amplification; NT on contiguous
// streams = full-line combining + no L2 pollution of the slab).
#define HC2       (1 << 18)
#define HMASK2    (HC2 - 1)
#define NSLOT2    (NB * HC2)       // 2,097,152 slots, 16 MB

#define IPT       4                 // points per thread in k_insert
#define ITILE     (256 * IPT)       // 1024 points per block
#define ITILES    ((NPB + ITILE - 1) / ITILE)   // 118

#define TILES     469              // ceil(120000 / 256)
#define TILES_PAD 512
#define MBCAP     8192             // per-batch multi list capacity (~500 expected)
#define MTILE     2048

#define EMPTY64   0xFFFFFFFFFFFFFFFFull

// output layout (flat float32)
#define OUT_VOX   0LL
#define OUT_NUM   12800000LL
#define OUT_COOR  13120000LL
#define OUT_GRID  14400000LL

typedef float f4v __attribute__((ext_vector_type(4)));

__device__ __forceinline__ bool point_cell(const float* __restrict__ p,
                                           int& cx, int& cy, int& cz) {
    // must match numpy f32: floor((xyz - PC_MIN) / VSIZE)
    cx = (int)floorf((p[1] - 0.0f)   / 0.1f);
    cy = (int)floorf((p[2] - (-40.0f)) / 0.1f);
    cz = (int)floorf((p[3] - (-3.0f))  / 0.2f);
    return (cx >= 0) & (cx < GX) & (cy >= 0) & (cy < GY) & (cz >= 0) & (cz < GZ);
}

__device__ __forceinline__ unsigned cell_hash(int lid) {
    return (((unsigned)lid * 2654435761u) >> 14) & HMASK2;
}

// ---------------- K0: init hash + flag + voxel zero-stream + mcount + grid ----------------
// Slab + flag via cached stores (want them L2-resident for k_insert).
// Voxel region (51.2 MB) via NT stores: contiguous lane-consecutive float4s
// (1 KB/wave full lines -> no amplification) that do NOT evict the slab.
__global__ void k_init(float* __restrict__ out, ulonglong2* __restrict__ slab2,
                       uint4* __restrict__ flag4, unsigned* __restrict__ mcount) {
    int b = blockIdx.x & 7;
    int i = (blockIdx.x >> 3) * 256 + threadIdx.x;     // 0..131071 per batch
    ulonglong2 e2; e2.x = EMPTY64; e2.y = EMPTY64;
    slab2[(size_t)b * (HC2 / 2) + i] = e2;             // 16 MB total
    if (i < NPB / 16) {                                // 7500 uint4 per batch
        uint4 o1; o1.x = o1.y = o1.z = o1.w = 0x01010101u;
        flag4[b * (NPB / 16) + i] = o1;                // flag = 1 (assume leader)
    }
    // contiguous NT zero-stream over the whole voxel region (12.8M floats)
    int t = blockIdx.x * blockDim.x + threadIdx.x;
    int stride = gridDim.x * blockDim.x;               // 1,048,576 threads
    f4v z = {0.f, 0.f, 0.f, 0.f};
    f4v* vox = (f4v*)(out + OUT_VOX);
    for (int j = t; j < 3200000; j += stride)          // 3.2M float4s = 51.2 MB
        __builtin_nontemporal_store(z, vox + j);
    if (blockIdx.x == 0 && threadIdx.x < NB) mcount[threadIdx.x * 16] = 0u;
    if (blockIdx.x == 0 && threadIdx.x == 0) {
        out[OUT_GRID + 0] = 704.f;
        out[OUT_GRID + 1] = 800.f;
        out[OUT_GRID + 2] = 20.f;
    }
}

// ---------------- K1: 4-way ILP robin-hood atomicMin insert + inline defeat-marking ----------------
__global__ void k_insert(const float* __restrict__ pts,
                         unsigned long long* __restrict__ slabB,
                         int* __restrict__ lid32, unsigned char* __restrict__ flag) {
    int b = blockIdx.x & 7;
    int base = (blockIdx.x >> 3) * ITILE + threadIdx.x;
    unsigned long long* tb = slabB + (size_t)b * HC2;

    unsigned long long key[IPT];
    unsigned h[IPT];
    bool act[IPT];
    #pragma unroll
    for (int k = 0; k < IPT; k++) {
        int idx = base + k * 256;
        act[k] = (idx < NPB);
        if (act[k]) {
            int g = b * NPB + idx;
            const float* p = pts + (long long)g * 5;
            int cx, cy, cz;
            bool v = point_cell(p, cx, cy, cz);
            if (v) {
                int lid = (cz * GY + cy) * GX + cx;
                lid32[g] = lid;
                h[k] = cell_hash(lid);
                key[k] = ((unsigned long long)(unsigned)lid << 32)
                       | (unsigned long long)(unsigned)idx;
            } else {
                lid32[g] = -1;
                flag[g] = 0;
                act[k] = false;
            }
        }
    }

    // issue all atomics back-to-back (independent; resolved below)
    unsigned long long old[IPT];
    #pragma unroll
    for (int k = 0; k < IPT; k++)
        if (act[k]) old[k] = atomicMin(&tb[h[k]], key[k]);

    #pragma unroll
    for (int k = 0; k < IPT; k++) {
        if (!act[k]) continue;
        unsigned long long kk = key[k];
        unsigned long long oo = old[k];
        unsigned hh = h[k];
        while (true) {
            if (oo == EMPTY64) break;                  // filled an empty slot
            if ((oo >> 32) == (kk >> 32)) {            // same cell: one idx defeated
                unsigned loser = (oo > kk) ? (unsigned)oo : (unsigned)kk;
                flag[b * NPB + (int)loser] = 0;        // rare (~480/batch)
                break;
            }
            if (oo > kk) kk = oo;                      // displaced foreign entry: carry it
            hh = (hh + 1) & HMASK2;
            oo = atomicMin(&tb[hh], kk);
        }
    }
}

// ---------------- K2: per-tile leader counts (1 wave per 256-point tile) ----------------
__global__ void k_count(const unsigned* __restrict__ flag32, int* __restrict__ tileSum) {
    int w = blockIdx.x * 4 + ((int)threadIdx.x >> 6);  // 0..3751
    int lane = threadIdx.x & 63;
    int b = w & 7;
    int tile = w >> 3;
    int i = tile * 64 + lane;                          // uint index within batch
    unsigned x = (i < NPB / 4) ? flag32[b * (NPB / 4) + i] : 0u;
    int s = (int)((x * 0x01010101u) >> 24);            // byte-sum (each byte 0/1)
    #pragma unroll
    for (int off = 32; off; off >>= 1) s += __shfl_down(s, off);
    if (lane == 0) tileSum[b * TILES_PAD + tile] = s;
}

// ---------------- K3: fused scans + leader writes; non-leaders -> mlist ----------------
// CACHED float4 stores (R4 lesson); only 11.5 MB written here now (row0 +
// coors + num), slot-sequential within each tile -> L2 write-combined.
// Rows 1..9 are already zero from k_init's NT stream.
__global__ void k_finish(const float* __restrict__ pts, const int* __restrict__ lid32,
                         const unsigned char* __restrict__ flag,
                         const int* __restrict__ tileSum,
                         const unsigned long long* __restrict__ slabB,
                         float* __restrict__ out, unsigned short* __restrict__ slotOf,
                         int2* __restrict__ mlist, unsigned* __restrict__ mcount) {
    int b = blockIdx.x & 7;
    int tile = blockIdx.x >> 3;
    int t = threadIdx.x;

    __shared__ int sc[256];
    __shared__ int soff[TILES_PAD];
    // --- scan A: exclusive scan over tile sums (pairs) ---
    int v0 = (2 * t     < TILES) ? tileSum[b * TILES_PAD + 2 * t]     : 0;
    int v1 = (2 * t + 1 < TILES) ? tileSum[b * TILES_PAD + 2 * t + 1] : 0;
    int w = v0 + v1;
    sc[t] = w;
    __syncthreads();
    for (int off = 1; off < 256; off <<= 1) {
        int x = sc[t];
        if (t >= off) x += sc[t - off];
        __syncthreads();
        sc[t] = x;
        __syncthreads();
    }
    int e = sc[t] - w;
    soff[2 * t] = e;
    soff[2 * t + 1] = e + v0;
    __syncthreads();

    // --- scan B: in-tile leader rank from flag ---
    int idx = tile * 256 + t;
    int g = b * NPB + idx;
    int f = (idx < NPB) ? (int)flag[g] : 0;
    sc[t] = f;
    __syncthreads();
    for (int off = 1; off < 256; off <<= 1) {
        int x = sc[t];
        if (t >= off) x += sc[t - off];
        __syncthreads();
        sc[t] = x;
        __syncthreads();
    }
    int rank = sc[t] - f;                      // exclusive in-tile rank
    // no __syncthreads below this point

    if (idx >= NPB) return;
    int lid = lid32[g];
    if (lid < 0) return;                       // invalid point

    if (f) {                                   // leader (== cell's min idx == pos 0)
        int slot = soff[tile] + rank;
        slotOf[g] = (unsigned short)(slot < 65535 ? slot : 65535);  // before clip!
        if (slot >= MAX_VOX) return;
        unsigned ul = (unsigned)lid;
        unsigned cx = ul % (unsigned)GX;
        unsigned tt = ul / (unsigned)GX;
        unsigned cy = tt % (unsigned)GY;
        unsigned cz = tt / (unsigned)GY;
        long long r = (long long)b * MAX_VOX + slot;
        ((float4*)(out + OUT_COOR))[r] = make_float4((float)b, (float)cz, (float)cy, (float)cx);
        out[OUT_NUM + r] = 1.f;                // multi corrected by k_multi
        const float* p = pts + (long long)g * 5;
        ((float4*)(out + OUT_VOX))[r * MAX_PTS] = make_float4(p[1], p[2], p[3], p[4]);
    } else {
        // valid non-leader => multi cell (rare, ~480/batch): probe for leader idx.
        const unsigned long long* base = slabB + (size_t)b * HC2;
        unsigned h = cell_hash(lid);
        unsigned long long cur;
        while (true) {
            cur = base[h];
            if ((unsigned)(cur >> 32) == (unsigned)lid) break;
            h = (h + 1) & HMASK2;
        }
        unsigned minidx = (unsigned)cur;
        unsigned m = atomicAdd(&mcount[b * 16], 1u);
        if (m < MBCAP) mlist[(size_t)b * MBCAP + m] = make_int2((int)minidx, idx);
    }
}

// ---------------- K4: rank + scatter multi-cell non-leaders; fix num ----------------
__global__ void k_multi(const float* __restrict__ pts,
                        const int2* __restrict__ mlist, const unsigned* __restrict__ mcount,
                        const unsigned short* __restrict__ slotOf,
                        float* __restrict__ out) {
    int b = blockIdx.y;
    unsigned n = mcount[b * 16];
    if (n > MBCAP) n = MBCAP;
    unsigned t = blockIdx.x * blockDim.x + threadIdx.x;
    const int2* lst = mlist + (size_t)b * MBCAP;
    bool active = (t < n);
    int2 e = active ? lst[t] : make_int2(-1, -1);   // (leaderIdx, idx)
    int pos = 1;                                    // leader (not in list) is pos 0
    int same = 0;                                   // same-cell entries incl. self
    __shared__ int2 sm[MTILE];
    for (unsigned chunk = 0; chunk < n; chunk += MTILE) {
        unsigned m = n - chunk;
        if (m > MTILE) m = MTILE;
        for (unsigned i = threadIdx.x; i < m; i += 256)
            sm[i] = lst[chunk + i];
        __syncthreads();
        if (active) {
            #pragma unroll 4
            for (unsigned j = 0; j < m; j++) {
                int2 o = sm[j];
                if (o.x == e.x) { same++; if (o.y < e.y) pos++; }
            }
        }
        __syncthreads();
    }
    if (!active) return;
    int slot = (int)slotOf[(size_t)b * NPB + e.x];
    if (slot >= MAX_VOX) return;
    if (pos == 1) {                                 // smallest non-leader writes true count
        int cnt = same + 1;                         // + leader
        out[OUT_NUM + (long long)b * MAX_VOX + slot] =
            (float)(cnt < MAX_PTS ? cnt : MAX_PTS);
    }
    if (pos >= MAX_PTS) return;
    const float* p = pts + ((long long)b * NPB + e.y) * 5;
    ((float4*)(out + OUT_VOX))[(long long)(b * MAX_VOX + slot) * MAX_PTS + pos] =
        make_float4(p[1], p[2], p[3], p[4]);
}

extern "C" void kernel_launch(void* const* d_in, const int* in_sizes, int n_in,
                              void* d_out, int out_size, void* d_ws, size_t ws_size,
                              hipStream_t stream) {
    const float* pts = (const float*)d_in[0];
    float* out = (float*)d_out;

    char* w = (char*)d_ws;
    unsigned long long* slabB = (unsigned long long*)w;
    w += (size_t)NSLOT2 * 8;                                               // 16 MB
    int2* mlist = (int2*)w;  w += (size_t)NB * MBCAP * 8;                  // 0.5 MB
    int* lid32 = (int*)w;    w += (size_t)NPTS * 4;                        // 3.84 MB
    int* tileSum = (int*)w;  w += (size_t)NB * TILES_PAD * 4;              // 16 KB
    unsigned* mcount = (unsigned*)w; w += (size_t)NB * 16 * 4;             // 512 B
    unsigned short* slotOf = (unsigned short*)w; w += (size_t)NPTS * 2;    // 1.92 MB
    unsigned char* flag = (unsigned char*)w;  w += (size_t)NPTS;           // 0.96 MB (16B-aligned)

    const int PB = TILES * NB;      // 3752 blocks for per-point kernels
    k_init<<<dim3(NB * (HC2 / 2 / 256)), dim3(256), 0, stream>>>(out, (ulonglong2*)slabB,
                                                                 (uint4*)flag, mcount);
    k_insert<<<dim3(ITILES * NB), dim3(256), 0, stream>>>(pts, slabB, lid32, flag);
    k_count<<<dim3((TILES * NB + 3) / 4), dim3(256), 0, stream>>>((const unsigned*)flag, tileSum);
    k_finish<<<dim3(PB), dim3(256), 0, stream>>>(pts, lid32, flag, tileSum, slabB,
                                                 out, slotOf, mlist, mcount);
    k_multi<<<dim3(MBCAP / 256, NB), dim3(256), 0, stream>>>(pts, mlist, mcount, slotOf, out);
}

// Round 6
// 164.076 us; speedup vs baseline: 1.5931x; 1.0775x over previous
//
#include <hip/hip_runtime.h>

// ---------------- problem constants ----------------
#define NB        8
#define NPB       120000
#define NPTS      (NB * NPB)       // 960000
#define MAX_PTS   10
#define MAX_VOX   40000
#define GX        704
#define GY        800
#define GZ        20
#define CELLS     (GX * GY * GZ)   // 11,264,000 cells per batch
#define WPB       (CELLS / 32)     // 352,000 bitmap words per batch

// R6: claim pass back to u32 atomicOr bitmap (R0 evidence: every phase1
// iteration < 42.6 us vs 53-61 us for ALL u64 atomicMin-hash variants, R1-R5).
// Device-scope RMW throughput is the wall (R5: 2x concurrency made it WORSE);
// u32 or-claim sustains ~1.4x the u64-min rate. Colliders (~480/batch) go to a
// tiny robin-hood hash; phase2 folds the claimer in so the hash ends holding
// the true leader idx for every multi cell.
#define HC2       (1 << 15)        // collider hash slots per batch (256 KB/batch)
#define HMASK2    (HC2 - 1)
#define NSLOT2    (NB * HC2)       // 262,144 slots, 2 MB

#define TILES     469              // ceil(120000 / 256)
#define TILES_PAD 512
#define MBCAP     8192             // per-batch multi list capacity (~500 expected)
#define MTILE     2048

#define EMPTY64   0xFFFFFFFFFFFFFFFFull

// output layout (flat float32)
#define OUT_VOX   0LL
#define OUT_NUM   12800000LL
#define OUT_COOR  13120000LL
#define OUT_GRID  14400000LL

typedef float f4v __attribute__((ext_vector_type(4)));

__device__ __forceinline__ bool point_cell(const float* __restrict__ p,
                                           int& cx, int& cy, int& cz) {
    // must match numpy f32: floor((xyz - PC_MIN) / VSIZE)
    cx = (int)floorf((p[1] - 0.0f)   / 0.1f);
    cy = (int)floorf((p[2] - (-40.0f)) / 0.1f);
    cz = (int)floorf((p[3] - (-3.0f))  / 0.2f);
    return (cx >= 0) & (cx < GX) & (cy >= 0) & (cy < GY) & (cz >= 0) & (cz < GZ);
}

__device__ __forceinline__ unsigned cell_hash(int lid) {
    return (((unsigned)lid * 2654435761u) >> 17) & HMASK2;
}

// ---------------- K0: init bitmap + hash + voxel zero-stream + mcount + grid ----------------
// Bitmap/hash via cached stores (want them L2-resident for the atomics).
// Voxel region (51.2 MB) via NT stores: contiguous lane-consecutive float4s
// (full-line combining, no L2 pollution). R4 lesson: NT only on contiguous
// streams, never scattered islands. No flag init: phase1 writes every byte.
__global__ void k_init(float* __restrict__ out, uint4* __restrict__ bm4,
                       ulonglong2* __restrict__ slab2, unsigned* __restrict__ mcount) {
    int t = blockIdx.x * blockDim.x + threadIdx.x;
    int stride = gridDim.x * blockDim.x;               // 524,288 threads
    uint4 z4 = make_uint4(0u, 0u, 0u, 0u);
    for (int i = t; i < NB * WPB / 4; i += stride) bm4[i] = z4;   // 11.26 MB
    ulonglong2 e2; e2.x = EMPTY64; e2.y = EMPTY64;
    if (t < NSLOT2 / 2) slab2[t] = e2;                            // 2 MB
    f4v z = {0.f, 0.f, 0.f, 0.f};
    f4v* vox = (f4v*)(out + OUT_VOX);
    for (int j = t; j < 3200000; j += stride)                     // 51.2 MB
        __builtin_nontemporal_store(z, vox + j);
    if (t < NB) mcount[t * 16] = 0u;                              // 64B-padded
    if (t == 0) {
        out[OUT_GRID + 0] = 704.f;
        out[OUT_GRID + 1] = 800.f;
        out[OUT_GRID + 2] = 20.f;
    }
}

// ---------------- K1: u32 atomicOr bitmap claim; colliders -> tiny hash ----------------
// XCD swizzle: batch = blockIdx & 7 -> batch b's 1.4 MB bitmap + 256 KB hash
// stay XCD-local (round-robin heuristic; correctness placement-independent).
__global__ void k_phase1(const float* __restrict__ pts, unsigned* __restrict__ bm,
                         unsigned long long* __restrict__ slabB,
                         unsigned char* __restrict__ flag, int* __restrict__ lid32) {
    int b = blockIdx.x & 7;
    int idx = (blockIdx.x >> 3) * 256 + threadIdx.x;
    if (idx >= NPB) return;
    int g = b * NPB + idx;
    const float* p = pts + (long long)g * 5;
    int cx, cy, cz;
    if (!point_cell(p, cx, cy, cz)) { flag[g] = 0; lid32[g] = -1; return; }
    int lid = (cz * GY + cy) * GX + cx;
    lid32[g] = lid;                                    // coalesced cache for later passes
    unsigned mask = 1u << (lid & 31);
    unsigned old = atomicOr(&bm[b * WPB + (lid >> 5)], mask);
    if ((old & mask) == 0u) {
        flag[g] = 1;                                   // claimer (provisional leader)
    } else {
        flag[g] = 0;                                   // collider: fold min into hash
        unsigned long long key = ((unsigned long long)(unsigned)lid << 32)
                               | (unsigned long long)(unsigned)idx;
        unsigned long long* base = slabB + (size_t)b * HC2;
        unsigned h = cell_hash(lid);
        while (true) {                                 // robin-hood atomicMin insert
            unsigned long long oo = atomicMin(base + h, key);
            if (oo == EMPTY64) break;                  // filled empty slot
            if ((oo >> 32) == (key >> 32)) break;      // same cell: min folded
            if (oo > key) key = oo;                    // displaced foreign: carry forward
            h = (h + 1) & HMASK2;
        }
    }
}

// ---------------- K2: claimers of collided cells resolve true leader ----------------
// Exactly one claimer per cell. atomicMin folds the claimer into the entry, so
// afterwards the hash holds the TRUE min idx (leader) for every collided cell
// (k_finish's non-leader probe relies on this). omin = min over phase1
// colliders; if omin < claimer idx, demote self and promote omin.
__global__ void k_phase2(const int* __restrict__ lid32, unsigned char* __restrict__ flag,
                         unsigned long long* __restrict__ slabB) {
    int b = blockIdx.x & 7;
    int idx = (blockIdx.x >> 3) * 256 + threadIdx.x;
    if (idx >= NPB) return;
    int g = b * NPB + idx;
    if (flag[g] != 1) return;                          // claimers only
    int lid = lid32[g];
    unsigned long long* base = slabB + (size_t)b * HC2;
    unsigned h = cell_hash(lid);
    while (true) {
        unsigned long long cur = base[h];
        if (cur == EMPTY64) break;                     // cell not collided: stay leader
        if ((unsigned)(cur >> 32) == (unsigned)lid) {
            unsigned long long key = ((unsigned long long)(unsigned)lid << 32)
                                   | (unsigned long long)(unsigned)idx;
            unsigned long long old = atomicMin(&base[h], key);
            unsigned omin = (unsigned)old;             // min over phase1 colliders
            if (omin < (unsigned)idx) {                // stolen: true leader is omin
                flag[g] = 0;
                flag[b * NPB + (int)omin] = 1;         // unique writer per cell
            }
            break;
        }
        h = (h + 1) & HMASK2;
    }
}

// ---------------- K3: per-tile leader counts (1 wave per 256-point tile) ----------------
__global__ void k_count(const unsigned* __restrict__ flag32, int* __restrict__ tileSum) {
    int w = blockIdx.x * 4 + ((int)threadIdx.x >> 6);  // 0..3751
    int lane = threadIdx.x & 63;
    int b = w & 7;
    int tile = w >> 3;
    int i = tile * 64 + lane;                          // uint index within batch
    unsigned x = (i < NPB / 4) ? flag32[b * (NPB / 4) + i] : 0u;
    int s = (int)((x * 0x01010101u) >> 24);            // byte-sum (each byte 0/1)
    #pragma unroll
    for (int off = 32; off; off >>= 1) s += __shfl_down(s, off);
    if (lane == 0) tileSum[b * TILES_PAD + tile] = s;
}

// ---------------- K4: fused scans + leader writes; non-leaders -> mlist ----------------
// CACHED float4 stores; only ~11.5 MB written here (row0 + coors + num),
// slot-sequential -> L2 write-combined. Rows 1..9 already zeroed by k_init.
__global__ void k_finish(const float* __restrict__ pts, const int* __restrict__ lid32,
                         const unsigned char* __restrict__ flag,
                         const int* __restrict__ tileSum,
                         const unsigned long long* __restrict__ slabB,
                         float* __restrict__ out, unsigned short* __restrict__ slotOf,
                         int2* __restrict__ mlist, unsigned* __restrict__ mcount) {
    int b = blockIdx.x & 7;
    int tile = blockIdx.x >> 3;
    int t = threadIdx.x;

    __shared__ int sc[256];
    __shared__ int soff[TILES_PAD];
    // --- scan A: exclusive scan over tile sums (pairs) ---
    int v0 = (2 * t     < TILES) ? tileSum[b * TILES_PAD + 2 * t]     : 0;
    int v1 = (2 * t + 1 < TILES) ? tileSum[b * TILES_PAD + 2 * t + 1] : 0;
    int w = v0 + v1;
    sc[t] = w;
    __syncthreads();
    for (int off = 1; off < 256; off <<= 1) {
        int x = sc[t];
        if (t >= off) x += sc[t - off];
        __syncthreads();
        sc[t] = x;
        __syncthreads();
    }
    int e = sc[t] - w;
    soff[2 * t] = e;
    soff[2 * t + 1] = e + v0;
    __syncthreads();

    // --- scan B: in-tile leader rank from flag ---
    int idx = tile * 256 + t;
    int g = b * NPB + idx;
    int f = (idx < NPB) ? (int)flag[g] : 0;
    sc[t] = f;
    __syncthreads();
    for (int off = 1; off < 256; off <<= 1) {
        int x = sc[t];
        if (t >= off) x += sc[t - off];
        __syncthreads();
        sc[t] = x;
        __syncthreads();
    }
    int rank = sc[t] - f;                      // exclusive in-tile rank
    // no __syncthreads below this point

    if (idx >= NPB) return;
    int lid = lid32[g];
    if (lid < 0) return;                       // invalid point

    if (f) {                                   // leader (== cell's min idx == pos 0)
        int slot = soff[tile] + rank;
        slotOf[g] = (unsigned short)(slot < 65535 ? slot : 65535);  // before clip!
        if (slot >= MAX_VOX) return;
        unsigned ul = (unsigned)lid;
        unsigned cx = ul % (unsigned)GX;
        unsigned tt = ul / (unsigned)GX;
        unsigned cy = tt % (unsigned)GY;
        unsigned cz = tt / (unsigned)GY;
        long long r = (long long)b * MAX_VOX + slot;
        ((float4*)(out + OUT_COOR))[r] = make_float4((float)b, (float)cz, (float)cy, (float)cx);
        out[OUT_NUM + r] = 1.f;                // multi corrected by k_multi
        const float* p = pts + (long long)g * 5;
        ((float4*)(out + OUT_VOX))[r * MAX_PTS] = make_float4(p[1], p[2], p[3], p[4]);
    } else {
        // valid non-leader => multi cell (rare, ~480/batch): probe for leader idx.
        // Post-phase2 the entry holds the true leader; entry guaranteed present.
        const unsigned long long* base = slabB + (size_t)b * HC2;
        unsigned h = cell_hash(lid);
        unsigned long long cur;
        while (true) {
            cur = base[h];
            if ((unsigned)(cur >> 32) == (unsigned)lid) break;
            h = (h + 1) & HMASK2;
        }
        unsigned minidx = (unsigned)cur;
        unsigned m = atomicAdd(&mcount[b * 16], 1u);
        if (m < MBCAP) mlist[(size_t)b * MBCAP + m] = make_int2((int)minidx, idx);
    }
}

// ---------------- K5: rank + scatter multi-cell non-leaders; fix num ----------------
// mlist entries are (leaderIdx, idx), leader never in list; slot via slotOf.
__global__ void k_multi(const float* __restrict__ pts,
                        const int2* __restrict__ mlist, const unsigned* __restrict__ mcount,
                        const unsigned short* __restrict__ slotOf,
                        float* __restrict__ out) {
    int b = blockIdx.y;
    unsigned n = mcount[b * 16];
    if (n > MBCAP) n = MBCAP;
    unsigned t = blockIdx.x * blockDim.x + threadIdx.x;
    const int2* lst = mlist + (size_t)b * MBCAP;
    bool active = (t < n);
    int2 e = active ? lst[t] : make_int2(-1, -1);   // (leaderIdx, idx)
    int pos = 1;                                    // leader (not in list) is pos 0
    int same = 0;                                   // same-cell entries incl. self
    __shared__ int2 sm[MTILE];
    for (unsigned chunk = 0; chunk < n; chunk += MTILE) {
        unsigned m = n - chunk;
        if (m > MTILE) m = MTILE;
        for (unsigned i = threadIdx.x; i < m; i += 256)
            sm[i] = lst[chunk + i];
        __syncthreads();
        if (active) {
            #pragma unroll 4
            for (unsigned j = 0; j < m; j++) {
                int2 o = sm[j];
                if (o.x == e.x) { same++; if (o.y < e.y) pos++; }
            }
        }
        __syncthreads();
    }
    if (!active) return;
    int slot = (int)slotOf[(size_t)b * NPB + e.x];
    if (slot >= MAX_VOX) return;
    if (pos == 1) {                                 // smallest non-leader writes true count
        int cnt = same + 1;                         // + leader
        out[OUT_NUM + (long long)b * MAX_VOX + slot] =
            (float)(cnt < MAX_PTS ? cnt : MAX_PTS);
    }
    if (pos >= MAX_PTS) return;
    const float* p = pts + ((long long)b * NPB + e.y) * 5;
    ((float4*)(out + OUT_VOX))[(long long)(b * MAX_VOX + slot) * MAX_PTS + pos] =
        make_float4(p[1], p[2], p[3], p[4]);
}

extern "C" void kernel_launch(void* const* d_in, const int* in_sizes, int n_in,
                              void* d_out, int out_size, void* d_ws, size_t ws_size,
                              hipStream_t stream) {
    const float* pts = (const float*)d_in[0];
    float* out = (float*)d_out;

    char* w = (char*)d_ws;
    unsigned* bm = (unsigned*)w;              w += (size_t)NB * WPB * 4;   // 11.26 MB
    unsigned long long* slabB = (unsigned long long*)w;
    w += (size_t)NSLOT2 * 8;                                               // 2 MB
    int2* mlist = (int2*)w;  w += (size_t)NB * MBCAP * 8;                  // 0.5 MB
    int* lid32 = (int*)w;    w += (size_t)NPTS * 4;                        // 3.84 MB
    int* tileSum = (int*)w;  w += (size_t)NB * TILES_PAD * 4;              // 16 KB
    unsigned* mcount = (unsigned*)w; w += (size_t)NB * 16 * 4;             // 512 B
    unsigned short* slotOf = (unsigned short*)w; w += (size_t)NPTS * 2;    // 1.92 MB
    unsigned char* flag = (unsigned char*)w;  w += (size_t)NPTS;           // 0.96 MB

    const int PB = TILES * NB;      // 3752 blocks for per-point kernels
    k_init<<<dim3(2048), dim3(256), 0, stream>>>(out, (uint4*)bm, (ulonglong2*)slabB, mcount);
    k_phase1<<<dim3(PB), dim3(256), 0, stream>>>(pts, bm, slabB, flag, lid32);
    k_phase2<<<dim3(PB), dim3(256), 0, stream>>>(lid32, flag, slabB);
    k_count<<<dim3((TILES * NB + 3) / 4), dim3(256), 0, stream>>>((const unsigned*)flag, tileSum);
    k_finish<<<dim3(PB), dim3(256), 0, stream>>>(pts, lid32, flag, tileSum, slabB,
                                                 out, slotOf, mlist, mcount);
    k_multi<<<dim3(MBCAP / 256, NB), dim3(256), 0, stream>>>(pts, mlist, mcount, slotOf, out);
}

// Round 7
// 153.139 us; speedup vs baseline: 1.7069x; 1.0714x over previous
//
#include <hip/hip_runtime.h>

// ---------------- problem constants ----------------
#define NB        8
#define NPB       120000
#define NPTS      (NB * NPB)       // 960000
#define MAX_PTS   10
#define MAX_VOX   40000
#define GX        704
#define GY        800
#define GZ        20

// R7: ATOMIC-FREE claim via plain-store last-writer-wins hash.
// R6 evidence: claim pass is device-RMW-throughput bound (op-sensitive,
// concurrency-insensitive). So: don't RMW. Every valid point plain-stores its
// idx into tbl0[h0(lid)] (per-batch 2^18 u32). Next kernel reads the winner w
// (stable) and verifies via lid32[w]: match -> cell claimed (w leader-cand,
// others register min in small slab); mismatch -> cell lost slot -> retry at
// level-1 table (2^16); level-2 survivors (~2k/batch) fall back to u64
// atomicMin slab insert (flag=3, resolved in phase2). Per-cell classification
// is uniform (all points of a cell read the same slot). No init needed for
// tbl0/tbl1: every slot read was written by the reader itself.
// Atomics: 960k -> ~25k. Stores are posted (no round trip).
#define T0        (1 << 18)
#define T0MASK    (T0 - 1)
#define T1        (1 << 16)
#define T1MASK    (T1 - 1)

#define HC2       (1 << 15)        // slab (min-hash) slots per batch
#define HMASK2    (HC2 - 1)
#define NSLOT2    (NB * HC2)       // 262,144 slots, 2 MB

#define TILES     469              // ceil(120000 / 256)
#define TILES_PAD 512
#define MBCAP     8192             // per-batch multi list capacity (~500 expected)
#define MTILE     2048

#define EMPTY64   0xFFFFFFFFFFFFFFFFull

// output layout (flat float32)
#define OUT_VOX   0LL
#define OUT_NUM   12800000LL
#define OUT_COOR  13120000LL
#define OUT_GRID  14400000LL

typedef float f4v __attribute__((ext_vector_type(4)));

__device__ __forceinline__ bool point_cell(const float* __restrict__ p,
                                           int& cx, int& cy, int& cz) {
    // must match numpy f32: floor((xyz - PC_MIN) / VSIZE)
    cx = (int)floorf((p[1] - 0.0f)   / 0.1f);
    cy = (int)floorf((p[2] - (-40.0f)) / 0.1f);
    cz = (int)floorf((p[3] - (-3.0f))  / 0.2f);
    return (cx >= 0) & (cx < GX) & (cy >= 0) & (cy < GY) & (cz >= 0) & (cz < GZ);
}

__device__ __forceinline__ unsigned hash0(int lid) {
    return (((unsigned)lid * 2654435761u) >> 14) & T0MASK;
}
__device__ __forceinline__ unsigned hash1(int lid) {
    return (((unsigned)lid * 0x9E3779B1u) >> 16) & T1MASK;
}
__device__ __forceinline__ unsigned slab_hash(int lid) {
    return (((unsigned)lid * 2654435761u) >> 17) & HMASK2;
}

// robin-hood atomicMin insert into the per-batch slab (min idx per cell)
__device__ __forceinline__ void slab_insert(unsigned long long* __restrict__ base,
                                            int lid, int idx) {
    unsigned long long key = ((unsigned long long)(unsigned)lid << 32)
                           | (unsigned long long)(unsigned)idx;
    unsigned h = slab_hash(lid);
    while (true) {
        unsigned long long oo = atomicMin(base + h, key);
        if (oo == EMPTY64) break;                  // filled empty slot
        if ((oo >> 32) == (key >> 32)) break;      // same cell: min folded
        if (oo > key) key = oo;                    // displaced foreign: carry forward
        h = (h + 1) & HMASK2;
    }
}

// ---------------- K0: init slab + voxel zero-stream + L0 claim-store ----------------
// tbl0 needs NO init (slots read in k1 were written by the reader). Voxel
// region (51.2 MB) NT-zeroed (contiguous full lines; R4 lesson). Claim store
// is a plain scattered u32 (posted, no round trip).
__global__ void k_init(const float* __restrict__ pts, float* __restrict__ out,
                       ulonglong2* __restrict__ slab2, unsigned* __restrict__ tbl0,
                       int* __restrict__ lid32, unsigned* __restrict__ mcount) {
    int b = blockIdx.x & 7;
    int idx = (blockIdx.x >> 3) * 256 + threadIdx.x;
    if (idx < NPB) {
        int g = b * NPB + idx;
        const float* p = pts + (long long)g * 5;
        int cx, cy, cz;
        if (point_cell(p, cx, cy, cz)) {
            int lid = (cz * GY + cy) * GX + cx;
            lid32[g] = lid;
            tbl0[b * T0 + hash0(lid)] = (unsigned)idx;   // last-writer-wins claim
        } else {
            lid32[g] = -1;
        }
    }
    int t = blockIdx.x * 256 + threadIdx.x;              // 960,512 threads
    int stride = gridDim.x * 256;
    f4v z = {0.f, 0.f, 0.f, 0.f};
    f4v* vox = (f4v*)(out + OUT_VOX);
    for (int j = t; j < 3200000; j += stride)            // 51.2 MB
        __builtin_nontemporal_store(z, vox + j);
    ulonglong2 e2; e2.x = EMPTY64; e2.y = EMPTY64;
    if (t < NSLOT2 / 2) slab2[t] = e2;                   // 2 MB
    if (t < NB) mcount[t * 16] = 0u;
    if (t == 0) {
        out[OUT_GRID + 0] = 704.f;
        out[OUT_GRID + 1] = 800.f;
        out[OUT_GRID + 2] = 20.f;
    }
}

// ---------------- K1: classify level-0; losers store level-1 claim ----------------
// flag: 1=leader-cand, 0=non-leader/invalid, 2=pending-L1.
__global__ void k_l0(const int* __restrict__ lid32, const unsigned* __restrict__ tbl0,
                     unsigned* __restrict__ tbl1, unsigned char* __restrict__ flag,
                     unsigned long long* __restrict__ slabB) {
    int b = blockIdx.x & 7;
    int idx = (blockIdx.x >> 3) * 256 + threadIdx.x;
    if (idx >= NPB) return;
    int g = b * NPB + idx;
    int lid = lid32[g];
    if (lid < 0) { flag[g] = 0; return; }
    unsigned w = tbl0[b * T0 + hash0(lid)];              // stable (no tbl0 writes here)
    if (lid32[b * NPB + (int)w] == lid) {                // our cell won the slot
        if (w == (unsigned)idx) flag[g] = 1;             // claimer
        else { flag[g] = 0; slab_insert(slabB + (size_t)b * HC2, lid, idx); }
    } else {                                             // slot stolen: retry at L1
        tbl1[b * T1 + hash1(lid)] = (unsigned)idx;
        flag[g] = 2;
    }
}

// ---------------- K2: classify level-1; survivors -> slab atomicMin (deferred) ----------------
__global__ void k_l1(const int* __restrict__ lid32, const unsigned* __restrict__ tbl1,
                     unsigned char* __restrict__ flag,
                     unsigned long long* __restrict__ slabB) {
    int b = blockIdx.x & 7;
    int idx = (blockIdx.x >> 3) * 256 + threadIdx.x;
    if (idx >= NPB) return;
    int g = b * NPB + idx;
    if (flag[g] != 2) return;                            // L1-pending only (~15%)
    int lid = lid32[g];
    unsigned w = tbl1[b * T1 + hash1(lid)];              // stable (written in k_l0)
    if (lid32[b * NPB + (int)w] == lid) {
        if (w == (unsigned)idx) flag[g] = 1;
        else { flag[g] = 0; slab_insert(slabB + (size_t)b * HC2, lid, idx); }
    } else {                                             // lost twice (~2k/batch): defer
        slab_insert(slabB + (size_t)b * HC2, lid, idx);
        flag[g] = 3;
    }
}

// ---------------- K3: claimer fold + deferred resolution ----------------
// Claimers (flag=1): probe slab; if their cell has an entry, fold own idx via
// atomicMin; if beaten, demote self, promote true leader (unique writer/cell).
// Deferred (flag=3): cell has no claimer; its slab entry is final after k_l1
// (folds only touch claimed cells' entries, lid fields never change, no
// displacement in this kernel) -> leader iff stored min == own idx.
__global__ void k_phase2(const int* __restrict__ lid32, unsigned char* __restrict__ flag,
                         unsigned long long* __restrict__ slabB) {
    int b = blockIdx.x & 7;
    int idx = (blockIdx.x >> 3) * 256 + threadIdx.x;
    if (idx >= NPB) return;
    int g = b * NPB + idx;
    unsigned char fl = flag[g];
    if (fl != 1 && fl != 3) return;
    int lid = lid32[g];
    unsigned long long* base = slabB + (size_t)b * HC2;
    unsigned h = slab_hash(lid);
    if (fl == 1) {
        while (true) {
            unsigned long long cur = base[h];
            if (cur == EMPTY64) break;                   // uncollided: stay leader
            if ((unsigned)(cur >> 32) == (unsigned)lid) {
                unsigned long long key = ((unsigned long long)(unsigned)lid << 32)
                                       | (unsigned long long)(unsigned)idx;
                unsigned long long old = atomicMin(&base[h], key);
                unsigned omin = (unsigned)old;
                if (omin < (unsigned)idx) {              // stolen: promote true leader
                    flag[g] = 0;
                    flag[b * NPB + (int)omin] = 1;
                }
                break;
            }
            h = (h + 1) & HMASK2;
        }
    } else {                                             // deferred
        while (true) {
            unsigned long long cur = base[h];
            if ((unsigned)(cur >> 32) == (unsigned)lid) {
                flag[g] = ((unsigned)cur == (unsigned)idx) ? 1 : 0;
                break;
            }
            h = (h + 1) & HMASK2;
        }
    }
}

// ---------------- K4: per-tile leader counts (1 wave per 256-point tile) ----------------
__global__ void k_count(const unsigned* __restrict__ flag32, int* __restrict__ tileSum) {
    int w = blockIdx.x * 4 + ((int)threadIdx.x >> 6);    // 0..3751
    int lane = threadIdx.x & 63;
    int b = w & 7;
    int tile = w >> 3;
    int i = tile * 64 + lane;
    unsigned x = (i < NPB / 4) ? flag32[b * (NPB / 4) + i] : 0u;
    int s = (int)((x * 0x01010101u) >> 24);              // byte-sum (each byte 0/1)
    #pragma unroll
    for (int off = 32; off; off >>= 1) s += __shfl_down(s, off);
    if (lane == 0) tileSum[b * TILES_PAD + tile] = s;
}

// ---------------- K5: fused scans + leader writes; non-leaders -> mlist ----------------
__global__ void k_finish(const float* __restrict__ pts, const int* __restrict__ lid32,
                         const unsigned char* __restrict__ flag,
                         const int* __restrict__ tileSum,
                         const unsigned long long* __restrict__ slabB,
                         float* __restrict__ out, unsigned short* __restrict__ slotOf,
                         int2* __restrict__ mlist, unsigned* __restrict__ mcount) {
    int b = blockIdx.x & 7;
    int tile = blockIdx.x >> 3;
    int t = threadIdx.x;

    __shared__ int sc[256];
    __shared__ int soff[TILES_PAD];
    // --- scan A: exclusive scan over tile sums (pairs) ---
    int v0 = (2 * t     < TILES) ? tileSum[b * TILES_PAD + 2 * t]     : 0;
    int v1 = (2 * t + 1 < TILES) ? tileSum[b * TILES_PAD + 2 * t + 1] : 0;
    int w = v0 + v1;
    sc[t] = w;
    __syncthreads();
    for (int off = 1; off < 256; off <<= 1) {
        int x = sc[t];
        if (t >= off) x += sc[t - off];
        __syncthreads();
        sc[t] = x;
        __syncthreads();
    }
    int e = sc[t] - w;
    soff[2 * t] = e;
    soff[2 * t + 1] = e + v0;
    __syncthreads();

    // --- scan B: in-tile leader rank from flag ---
    int idx = tile * 256 + t;
    int g = b * NPB + idx;
    int f = (idx < NPB) ? (int)flag[g] : 0;
    sc[t] = f;
    __syncthreads();
    for (int off = 1; off < 256; off <<= 1) {
        int x = sc[t];
        if (t >= off) x += sc[t - off];
        __syncthreads();
        sc[t] = x;
        __syncthreads();
    }
    int rank = sc[t] - f;                      // exclusive in-tile rank
    // no __syncthreads below this point

    if (idx >= NPB) return;
    int lid = lid32[g];
    if (lid < 0) return;

    if (f) {                                   // leader
        int slot = soff[tile] + rank;
        slotOf[g] = (unsigned short)(slot < 65535 ? slot : 65535);
        if (slot >= MAX_VOX) return;
        unsigned ul = (unsigned)lid;
        unsigned cx = ul % (unsigned)GX;
        unsigned tt = ul / (unsigned)GX;
        unsigned cy = tt % (unsigned)GY;
        unsigned cz = tt / (unsigned)GY;
        long long r = (long long)b * MAX_VOX + slot;
        ((float4*)(out + OUT_COOR))[r] = make_float4((float)b, (float)cz, (float)cy, (float)cx);
        out[OUT_NUM + r] = 1.f;                // multi corrected by k_multi
        const float* p = pts + (long long)g * 5;
        ((float4*)(out + OUT_VOX))[r * MAX_PTS] = make_float4(p[1], p[2], p[3], p[4]);
    } else {
        // valid non-leader => multi cell: slab entry holds true leader idx
        const unsigned long long* base = slabB + (size_t)b * HC2;
        unsigned h = slab_hash(lid);
        unsigned long long cur;
        while (true) {
            cur = base[h];
            if ((unsigned)(cur >> 32) == (unsigned)lid) break;
            h = (h + 1) & HMASK2;
        }
        unsigned minidx = (unsigned)cur;
        unsigned m = atomicAdd(&mcount[b * 16], 1u);
        if (m < MBCAP) mlist[(size_t)b * MBCAP + m] = make_int2((int)minidx, idx);
    }
}

// ---------------- K6: rank + scatter multi-cell non-leaders; fix num ----------------
__global__ void k_multi(const float* __restrict__ pts,
                        const int2* __restrict__ mlist, const unsigned* __restrict__ mcount,
                        const unsigned short* __restrict__ slotOf,
                        float* __restrict__ out) {
    int b = blockIdx.y;
    unsigned n = mcount[b * 16];
    if (n > MBCAP) n = MBCAP;
    unsigned t = blockIdx.x * blockDim.x + threadIdx.x;
    const int2* lst = mlist + (size_t)b * MBCAP;
    bool active = (t < n);
    int2 e = active ? lst[t] : make_int2(-1, -1);   // (leaderIdx, idx)
    int pos = 1;
    int same = 0;
    __shared__ int2 sm[MTILE];
    for (unsigned chunk = 0; chunk < n; chunk += MTILE) {
        unsigned m = n - chunk;
        if (m > MTILE) m = MTILE;
        for (unsigned i = threadIdx.x; i < m; i += 256)
            sm[i] = lst[chunk + i];
        __syncthreads();
        if (active) {
            #pragma unroll 4
            for (unsigned j = 0; j < m; j++) {
                int2 o = sm[j];
                if (o.x == e.x) { same++; if (o.y < e.y) pos++; }
            }
        }
        __syncthreads();
    }
    if (!active) return;
    int slot = (int)slotOf[(size_t)b * NPB + e.x];
    if (slot >= MAX_VOX) return;
    if (pos == 1) {
        int cnt = same + 1;
        out[OUT_NUM + (long long)b * MAX_VOX + slot] =
            (float)(cnt < MAX_PTS ? cnt : MAX_PTS);
    }
    if (pos >= MAX_PTS) return;
    const float* p = pts + ((long long)b * NPB + e.y) * 5;
    ((float4*)(out + OUT_VOX))[(long long)(b * MAX_VOX + slot) * MAX_PTS + pos] =
        make_float4(p[1], p[2], p[3], p[4]);
}

extern "C" void kernel_launch(void* const* d_in, const int* in_sizes, int n_in,
                              void* d_out, int out_size, void* d_ws, size_t ws_size,
                              hipStream_t stream) {
    const float* pts = (const float*)d_in[0];
    float* out = (float*)d_out;

    char* w = (char*)d_ws;
    unsigned* tbl0 = (unsigned*)w;            w += (size_t)NB * T0 * 4;    // 8 MB (no init)
    unsigned* tbl1 = (unsigned*)w;            w += (size_t)NB * T1 * 4;    // 2 MB (no init)
    unsigned long long* slabB = (unsigned long long*)w;
    w += (size_t)NSLOT2 * 8;                                               // 2 MB
    int2* mlist = (int2*)w;  w += (size_t)NB * MBCAP * 8;                  // 0.5 MB
    int* lid32 = (int*)w;    w += (size_t)NPTS * 4;                        // 3.84 MB
    int* tileSum = (int*)w;  w += (size_t)NB * TILES_PAD * 4;              // 16 KB
    unsigned* mcount = (unsigned*)w; w += (size_t)NB * 16 * 4;             // 512 B
    unsigned short* slotOf = (unsigned short*)w; w += (size_t)NPTS * 2;    // 1.92 MB
    unsigned char* flag = (unsigned char*)w;  w += (size_t)NPTS;           // 0.96 MB

    const int PB = TILES * NB;      // 3752 blocks for per-point kernels
    k_init<<<dim3(PB), dim3(256), 0, stream>>>(pts, out, (ulonglong2*)slabB, tbl0, lid32, mcount);
    k_l0<<<dim3(PB), dim3(256), 0, stream>>>(lid32, tbl0, tbl1, flag, slabB);
    k_l1<<<dim3(PB), dim3(256), 0, stream>>>(lid32, tbl1, flag, slabB);
    k_phase2<<<dim3(PB), dim3(256), 0, stream>>>(lid32, flag, slabB);
    k_count<<<dim3((TILES * NB + 3) / 4), dim3(256), 0, stream>>>((const unsigned*)flag, tileSum);
    k_finish<<<dim3(PB), dim3(256), 0, stream>>>(pts, lid32, flag, tileSum, slabB,
                                                 out, slotOf, mlist, mcount);
    k_multi<<<dim3(MBCAP / 256, NB), dim3(256), 0, stream>>>(pts, mlist, mcount, slotOf, out);
}